// Round 10
// baseline (205.349 us; speedup 1.0000x reference)
//
#include <hip/hip_runtime.h>

#define N_DATA   128
#define SEG_LEN  131072
#define NPROD    (SEG_LEN - 1)
#define N_MAT    8
#define N_MATP   8
#define N_PROCP  5
#define RGAS     8.314f
#define LOG2E    1.44269504f

#define NCH      32          // chunks per row
#define CHUNK    4096        // elements per chunk
#define TPB      256
#define EPT      16          // CHUNK / TPB

typedef float nt4 __attribute__((ext_vector_type(4)));

// HW transcendentals (avoid glibc macro collisions with __exp2f/__log2f):
//   amd_exp2(x) = 2^x, amd_log2(x) = log2(x)
#define amd_exp2(x) __builtin_amdgcn_exp2f(x)
#define amd_log2(x) __builtin_amdgcn_logf(x)

// All per-row constants are folded so the inner loop touches RAW x only:
//   log-arg  = x*c_la + c_lb          (= t/200 + 0.001)
//   exp2-arg = x*c_ea + c_eb          (= -t*inv_tau*log2e)
//   s_scaled = (bn_s*(u*Lg) + s0cbd_s)/(Lg*(u+cbd)) + A0_s*2^exparg
//   p        = s_scaled * (x[k+1]-x[k])    -- already in FINAL output units
// (x_sc and inv_yr are folded into bn_s / s0cbd_s / A0_s; chunk sums are
// final-scaled too, so K2's fixup add is unit-consistent.)
struct RowK {
  float c_la, c_lb, alpha1, L0, G200, R, cbd, bn_s, s0cbd_s, A0_s, c_ea, c_eb, K0_s;
};

__device__ __forceinline__ RowK derive(const float pv[13],
    const float* __restrict__ pc, const float* __restrict__ sc, int row) {
  RowK k;
  float SigmaC = pv[0], K0 = pv[1];
  k.alpha1 = pv[2]; k.L0 = pv[3]; k.G200 = pv[4];
  float Sigma0 = pv[5], BetaD = pv[6], Ea = pv[7], Mfda = pv[8], Di = pv[9];
  float A0 = pv[10], B0 = pv[11], l0 = pv[12];
  k.R = pc[row * 4 + 0];
  float T = pc[row * 4 + 1], P = pc[row * 4 + 2];
  float x_min = sc[0], x_sc = sc[1] - sc[0];
  float y_min = sc[2], inv_yr = 1.0f / (sc[3] - sc[2]);
  float S = x_sc * inv_yr;                       // global fold factor
  k.cbd     = BetaD * Di * __expf(-Ea / (RGAS * T));
  k.bn_s    = (SigmaC - Mfda * P) * S;
  k.s0cbd_s = Sigma0 * k.cbd * S;
  float inv_tau = 1.0f / (B0 * l0 + 1e-9f);
  k.A0_s    = A0 * S;
  k.c_la    = x_sc * (1.0f / 200.0f);
  k.c_lb    = x_min * (1.0f / 200.0f) + 0.001f;
  k.c_ea    = -x_sc * inv_tau * LOG2E;
  k.c_eb    = -x_min * inv_tau * LOG2E;
  k.K0_s    = (K0 - y_min) * inv_yr;
  return k;
}

__device__ __forceinline__ float sprod(float xk, float xk1, const RowK& c) {
  float zl  = xk * c.c_la + c.c_lb;
  float Lg  = c.G200 * amd_exp2(c.alpha1 * amd_log2(zl)) + c.L0;
  float u   = c.R * Lg + 1e-9f;
  float num = c.bn_s * (u * Lg) + c.s0cbd_s;
  float den = Lg * (u + c.cbd);
  float e   = amd_exp2(xk * c.c_ea + c.c_eb);
  float s   = num * __builtin_amdgcn_rcpf(den) + c.A0_s * e;
  return s * (xk1 - xk);
}

// K1: chunk sums only (final-scaled units). Compute-bound.
__global__ __launch_bounds__(TPB) void k1_sums(
    const float* __restrict__ x,
    const float* __restrict__ pc, const float* __restrict__ raw,
    const float* __restrict__ lb, const float* __restrict__ ub,
    const float* __restrict__ sc, const int* __restrict__ mat_idx,
    float* __restrict__ chunksum) {
  __shared__ float pv[13];
  __shared__ float ws4[4];

  int b   = blockIdx.x;
  int row = b >> 5;
  int ch  = b & (NCH - 1);
  int tid = threadIdx.x;
  int lane = tid & 63, wv = tid >> 6;

  long rowbase = (long)row * SEG_LEN;
  int  gb = ch * CHUNK + tid * EPT;
  const float* xp = x + rowbase + gb;
  float xv[EPT + 1];
  { float4 q0 = *(const float4*)xp;       xv[0]=q0.x; xv[1]=q0.y; xv[2]=q0.z; xv[3]=q0.w;
    float4 q1 = *(const float4*)(xp + 4); xv[4]=q1.x; xv[5]=q1.y; xv[6]=q1.z; xv[7]=q1.w;
    float4 q2 = *(const float4*)(xp + 8); xv[8]=q2.x; xv[9]=q2.y; xv[10]=q2.z; xv[11]=q2.w;
    float4 q3 = *(const float4*)(xp +12); xv[12]=q3.x; xv[13]=q3.y; xv[14]=q3.z; xv[15]=q3.w;
    xv[16] = (gb + EPT < SEG_LEN) ? xp[EPT] : 0.0f; }

  if (tid < 13) {
    int idx = (tid < 5) ? (N_MAT * N_MATP + row * N_PROCP + tid)
                        : (mat_idx[row] * N_MATP + (tid - 5));
    float s = 1.0f / (1.0f + __expf(-raw[idx]));
    pv[tid] = s * (ub[idx] - lb[idx]) + lb[idx];
  }
  __syncthreads();
  RowK c = derive(pv, pc, sc, row);

  float sum = 0.0f;
#pragma unroll
  for (int k = 0; k < EPT; k++)
    if (gb + k < NPROD) sum += sprod(xv[k], xv[k + 1], c);

#pragma unroll
  for (int d = 32; d > 0; d >>= 1) sum += __shfl_down(sum, d);
  if (lane == 0) ws4[wv] = sum;
  __syncthreads();
  if (tid == 0) chunksum[b] = ws4[0] + ws4[1] + ws4[2] + ws4[3];
}

// K2: recompute products, add chunk offset (in-register wave scan of 32
// L2-hot chunk sums), write final output. out[i] = K0_s + prefix(i-1):
// thread t stores [gb, gb+16) = base + {0, pref[0..14]} -> 4 aligned NT stores.
__global__ __launch_bounds__(TPB) void k2_write(
    const float* __restrict__ x,
    const float* __restrict__ pc, const float* __restrict__ raw,
    const float* __restrict__ lb, const float* __restrict__ ub,
    const float* __restrict__ sc, const int* __restrict__ mat_idx,
    const float* __restrict__ chunksum,
    float* __restrict__ out) {
  __shared__ float pv[13];
  __shared__ float wtot[4];

  int b   = blockIdx.x;
  int row = b >> 5;
  int ch  = b & (NCH - 1);
  int tid = threadIdx.x;
  int lane = tid & 63, wv = tid >> 6;

  long rowbase = (long)row * SEG_LEN;
  int  gb = ch * CHUNK + tid * EPT;
  const float* xp = x + rowbase + gb;
  float xv[EPT + 1];
  { float4 q0 = *(const float4*)xp;       xv[0]=q0.x; xv[1]=q0.y; xv[2]=q0.z; xv[3]=q0.w;
    float4 q1 = *(const float4*)(xp + 4); xv[4]=q1.x; xv[5]=q1.y; xv[6]=q1.z; xv[7]=q1.w;
    float4 q2 = *(const float4*)(xp + 8); xv[8]=q2.x; xv[9]=q2.y; xv[10]=q2.z; xv[11]=q2.w;
    float4 q3 = *(const float4*)(xp +12); xv[12]=q3.x; xv[13]=q3.y; xv[14]=q3.z; xv[15]=q3.w;
    xv[16] = (gb + EPT < SEG_LEN) ? xp[EPT] : 0.0f; }
  float csv = chunksum[(row << 5) | (lane & 31)];

  if (tid < 13) {
    int idx = (tid < 5) ? (N_MAT * N_MATP + row * N_PROCP + tid)
                        : (mat_idx[row] * N_MATP + (tid - 5));
    float s = 1.0f / (1.0f + __expf(-raw[idx]));
    pv[tid] = s * (ub[idx] - lb[idx]) + lb[idx];
  }

  // 32-wide exclusive scan of chunk sums (lanes >=32 compute garbage, unused)
  float cincl = csv;
#pragma unroll
  for (int d = 1; d < 32; d <<= 1) {
    float n = __shfl_up(cincl, d);
    if ((lane & 31) >= d) cincl += n;
  }
  float choff = __shfl(cincl - csv, ch);   // exclusive prefix of chunk ch (<32)

  __syncthreads();
  RowK c = derive(pv, pc, sc, row);

  float pref[EPT];
  float run = 0.0f;
#pragma unroll
  for (int k = 0; k < EPT; k++) {
    float p = (gb + k < NPROD) ? sprod(xv[k], xv[k + 1], c) : 0.0f;
    run += p;
    pref[k] = run;
  }

  float incl = run;
#pragma unroll
  for (int d = 1; d < 64; d <<= 1) {
    float n = __shfl_up(incl, d);
    if (lane >= d) incl += n;
  }
  if (lane == 63) wtot[wv] = incl;
  __syncthreads();
  float low = 0.0f;
#pragma unroll
  for (int w = 0; w < 4; w++) low += (w < wv) ? wtot[w] : 0.0f;

  float base = c.K0_s + choff + (incl - run) + low;
  nt4* op = (nt4*)(out + rowbase + gb);
#pragma unroll
  for (int j = 0; j < EPT / 4; j++) {
    int m = j * 4;
    nt4 o;
    o.x = (m == 0) ? base : base + pref[m - 1];
    o.y = base + pref[m + 0];
    o.z = base + pref[m + 1];
    o.w = base + pref[m + 2];
    __builtin_nontemporal_store(o, op + j);
  }
}

extern "C" void kernel_launch(void* const* d_in, const int* in_sizes, int n_in,
                              void* d_out, int out_size, void* d_ws, size_t ws_size,
                              hipStream_t stream) {
  const float* x_scaled  = (const float*)d_in[0];
  const float* process_c = (const float*)d_in[1];
  const float* raw       = (const float*)d_in[2];
  const float* lb        = (const float*)d_in[3];
  const float* ub        = (const float*)d_in[4];
  const float* sc        = (const float*)d_in[5];
  // d_in[6] = fit_index (unused by the reference computation)
  const int*   mat_idx   = (const int*)d_in[7];
  float* out = (float*)d_out;
  float* chunksum = (float*)d_ws;   // 4096 floats, fully rewritten every launch

  k1_sums<<<N_DATA * NCH, TPB, 0, stream>>>(
      x_scaled, process_c, raw, lb, ub, sc, mat_idx, chunksum);
  k2_write<<<N_DATA * NCH, TPB, 0, stream>>>(
      x_scaled, process_c, raw, lb, ub, sc, mat_idx, chunksum, out);
}

// Round 11
// 192.535 us; speedup vs baseline: 1.0665x; 1.0665x over previous
//
#include <hip/hip_runtime.h>

#define N_DATA   128
#define SEG_LEN  131072
#define NPROD    (SEG_LEN - 1)
#define N_MAT    8
#define N_MATP   8
#define N_PROCP  5
#define RGAS     8.314f
#define LOG2E    1.44269504f

#define NCH      32          // chunks per row
#define CHUNK    4096        // elements per chunk
#define TPB      256
#define EPT      16          // CHUNK / TPB

// HW transcendentals (avoid glibc macro collisions with __exp2f/__log2f):
#define amd_exp2(x) __builtin_amdgcn_exp2f(x)
#define amd_log2(x) __builtin_amdgcn_logf(x)

// Folded per-row constants; inner loop touches RAW x only. x_sc and inv_yr are
// folded into bn_s/s0cbd_s/A0_s so products are born in final output units.
struct RowK {
  float c_la, c_lb, alpha1, L0, G200, R, cbd, bn_s, s0cbd_s, A0_s, c_ea, c_eb, K0_s;
};

__device__ __forceinline__ RowK derive(const float pv[13],
    const float* __restrict__ pc, const float* __restrict__ sc, int row) {
  RowK k;
  float SigmaC = pv[0], K0 = pv[1];
  k.alpha1 = pv[2]; k.L0 = pv[3]; k.G200 = pv[4];
  float Sigma0 = pv[5], BetaD = pv[6], Ea = pv[7], Mfda = pv[8], Di = pv[9];
  float A0 = pv[10], B0 = pv[11], l0 = pv[12];
  k.R = pc[row * 4 + 0];
  float T = pc[row * 4 + 1], P = pc[row * 4 + 2];
  float x_min = sc[0], x_sc = sc[1] - sc[0];
  float y_min = sc[2], inv_yr = 1.0f / (sc[3] - sc[2]);
  float S = x_sc * inv_yr;
  k.cbd     = BetaD * Di * __expf(-Ea / (RGAS * T));
  k.bn_s    = (SigmaC - Mfda * P) * S;
  k.s0cbd_s = Sigma0 * k.cbd * S;
  float inv_tau = 1.0f / (B0 * l0 + 1e-9f);
  k.A0_s    = A0 * S;
  k.c_la    = x_sc * (1.0f / 200.0f);
  k.c_lb    = x_min * (1.0f / 200.0f) + 0.001f;
  k.c_ea    = -x_sc * inv_tau * LOG2E;
  k.c_eb    = -x_min * inv_tau * LOG2E;
  k.K0_s    = (K0 - y_min) * inv_yr;
  return k;
}

__device__ __forceinline__ float sprod(float xk, float xk1, const RowK& c) {
  float zl  = xk * c.c_la + c.c_lb;
  float Lg  = c.G200 * amd_exp2(c.alpha1 * amd_log2(zl)) + c.L0;
  float u   = c.R * Lg + 1e-9f;
  float num = c.bn_s * (u * Lg) + c.s0cbd_s;
  float den = Lg * (u + c.cbd);
  float e   = amd_exp2(xk * c.c_ea + c.c_eb);
  float s   = num * __builtin_amdgcn_rcpf(den) + c.A0_s * e;
  return s * (xk1 - xk);
}

// K1: chunk sums only (final-scaled units). Compute-bound.
__global__ __launch_bounds__(TPB) void k1_sums(
    const float* __restrict__ x,
    const float* __restrict__ pc, const float* __restrict__ raw,
    const float* __restrict__ lb, const float* __restrict__ ub,
    const float* __restrict__ sc, const int* __restrict__ mat_idx,
    float* __restrict__ chunksum) {
  __shared__ float pv[13];
  __shared__ float ws4[4];

  int b   = blockIdx.x;
  int row = b >> 5;
  int ch  = b & (NCH - 1);
  int tid = threadIdx.x;
  int lane = tid & 63, wv = tid >> 6;

  long rowbase = (long)row * SEG_LEN;
  int  gb = ch * CHUNK + tid * EPT;
  const float* xp = x + rowbase + gb;
  float xv[EPT + 1];
  { float4 q0 = *(const float4*)xp;       xv[0]=q0.x; xv[1]=q0.y; xv[2]=q0.z; xv[3]=q0.w;
    float4 q1 = *(const float4*)(xp + 4); xv[4]=q1.x; xv[5]=q1.y; xv[6]=q1.z; xv[7]=q1.w;
    float4 q2 = *(const float4*)(xp + 8); xv[8]=q2.x; xv[9]=q2.y; xv[10]=q2.z; xv[11]=q2.w;
    float4 q3 = *(const float4*)(xp +12); xv[12]=q3.x; xv[13]=q3.y; xv[14]=q3.z; xv[15]=q3.w;
    xv[16] = (gb + EPT < SEG_LEN) ? xp[EPT] : 0.0f; }

  if (tid < 13) {
    int idx = (tid < 5) ? (N_MAT * N_MATP + row * N_PROCP + tid)
                        : (mat_idx[row] * N_MATP + (tid - 5));
    float s = 1.0f / (1.0f + __expf(-raw[idx]));
    pv[tid] = s * (ub[idx] - lb[idx]) + lb[idx];
  }
  __syncthreads();
  RowK c = derive(pv, pc, sc, row);

  float sum = 0.0f;
  if (ch != NCH - 1) {            // wave-uniform: full chunk, no per-element guard
#pragma unroll
    for (int k = 0; k < EPT; k++) sum += sprod(xv[k], xv[k + 1], c);
  } else {
#pragma unroll
    for (int k = 0; k < EPT; k++)
      if (gb + k < NPROD) sum += sprod(xv[k], xv[k + 1], c);
  }

#pragma unroll
  for (int d = 32; d > 0; d >>= 1) sum += __shfl_down(sum, d);
  if (lane == 0) ws4[wv] = sum;
  __syncthreads();
  if (tid == 0) chunksum[b] = ws4[0] + ws4[1] + ws4[2] + ws4[3];
}

// K2: recompute products, add chunk offset (in-register wave scan of 32
// L2-hot chunk sums), write final output with plain cached float4 stores
// (L2 write-combines the stride-interleaved 16B chunks into full lines --
// NT stores caused 2x HBM write amplification, measured R10).
__global__ __launch_bounds__(TPB) void k2_write(
    const float* __restrict__ x,
    const float* __restrict__ pc, const float* __restrict__ raw,
    const float* __restrict__ lb, const float* __restrict__ ub,
    const float* __restrict__ sc, const int* __restrict__ mat_idx,
    const float* __restrict__ chunksum,
    float* __restrict__ out) {
  __shared__ float pv[13];
  __shared__ float wtot[4];

  int b   = blockIdx.x;
  int row = b >> 5;
  int ch  = b & (NCH - 1);
  int tid = threadIdx.x;
  int lane = tid & 63, wv = tid >> 6;

  long rowbase = (long)row * SEG_LEN;
  int  gb = ch * CHUNK + tid * EPT;
  const float* xp = x + rowbase + gb;
  float xv[EPT + 1];
  { float4 q0 = *(const float4*)xp;       xv[0]=q0.x; xv[1]=q0.y; xv[2]=q0.z; xv[3]=q0.w;
    float4 q1 = *(const float4*)(xp + 4); xv[4]=q1.x; xv[5]=q1.y; xv[6]=q1.z; xv[7]=q1.w;
    float4 q2 = *(const float4*)(xp + 8); xv[8]=q2.x; xv[9]=q2.y; xv[10]=q2.z; xv[11]=q2.w;
    float4 q3 = *(const float4*)(xp +12); xv[12]=q3.x; xv[13]=q3.y; xv[14]=q3.z; xv[15]=q3.w;
    xv[16] = (gb + EPT < SEG_LEN) ? xp[EPT] : 0.0f; }
  float csv = chunksum[(row << 5) | (lane & 31)];

  if (tid < 13) {
    int idx = (tid < 5) ? (N_MAT * N_MATP + row * N_PROCP + tid)
                        : (mat_idx[row] * N_MATP + (tid - 5));
    float s = 1.0f / (1.0f + __expf(-raw[idx]));
    pv[tid] = s * (ub[idx] - lb[idx]) + lb[idx];
  }

  // 32-wide exclusive scan of chunk sums (lanes >=32 compute garbage, unused)
  float cincl = csv;
#pragma unroll
  for (int d = 1; d < 32; d <<= 1) {
    float n = __shfl_up(cincl, d);
    if ((lane & 31) >= d) cincl += n;
  }
  float choff = __shfl(cincl - csv, ch);   // exclusive prefix of chunk ch (<32)

  __syncthreads();
  RowK c = derive(pv, pc, sc, row);

  float pref[EPT];
  float run = 0.0f;
  if (ch != NCH - 1) {
#pragma unroll
    for (int k = 0; k < EPT; k++) {
      run += sprod(xv[k], xv[k + 1], c);
      pref[k] = run;
    }
  } else {
#pragma unroll
    for (int k = 0; k < EPT; k++) {
      float p = (gb + k < NPROD) ? sprod(xv[k], xv[k + 1], c) : 0.0f;
      run += p;
      pref[k] = run;
    }
  }

  float incl = run;
#pragma unroll
  for (int d = 1; d < 64; d <<= 1) {
    float n = __shfl_up(incl, d);
    if (lane >= d) incl += n;
  }
  if (lane == 63) wtot[wv] = incl;
  __syncthreads();
  float low = 0.0f;
#pragma unroll
  for (int w = 0; w < 4; w++) low += (w < wv) ? wtot[w] : 0.0f;

  // out[i] = K0_s + prefix(i-1): thread t stores [gb, gb+16) as 4 aligned float4
  float base = c.K0_s + choff + (incl - run) + low;
  float* op = out + rowbase + gb;
#pragma unroll
  for (int j = 0; j < EPT / 4; j++) {
    int m = j * 4;
    float4 o;
    o.x = (m == 0) ? base : base + pref[m - 1];
    o.y = base + pref[m + 0];
    o.z = base + pref[m + 1];
    o.w = base + pref[m + 2];
    *(float4*)(op + m) = o;
  }
}

extern "C" void kernel_launch(void* const* d_in, const int* in_sizes, int n_in,
                              void* d_out, int out_size, void* d_ws, size_t ws_size,
                              hipStream_t stream) {
  const float* x_scaled  = (const float*)d_in[0];
  const float* process_c = (const float*)d_in[1];
  const float* raw       = (const float*)d_in[2];
  const float* lb        = (const float*)d_in[3];
  const float* ub        = (const float*)d_in[4];
  const float* sc        = (const float*)d_in[5];
  // d_in[6] = fit_index (unused by the reference computation)
  const int*   mat_idx   = (const int*)d_in[7];
  float* out = (float*)d_out;
  float* chunksum = (float*)d_ws;   // 4096 floats, fully rewritten every launch

  k1_sums<<<N_DATA * NCH, TPB, 0, stream>>>(
      x_scaled, process_c, raw, lb, ub, sc, mat_idx, chunksum);
  k2_write<<<N_DATA * NCH, TPB, 0, stream>>>(
      x_scaled, process_c, raw, lb, ub, sc, mat_idx, chunksum, out);
}